// Round 7
// baseline (470.661 us; speedup 1.0000x reference)
//
#include <hip/hip_runtime.h>
#include <hip/hip_bf16.h>
#include <cstdint>
#include <cstddef>

// Problem constants (DeepseekV3Experts: T=1024 H=1024 I=1408 E=8 K=4)
#define NE 8
#define NT 1024
#define NK 4
#define NH 1024
#define NI 1408
#define NA (NT * NK)      // 4096 assignments
#define BM 128            // row tile
#define MAXTILES 40
#define PADSLOTS 5120

typedef short short8 __attribute__((ext_vector_type(8)));
typedef float f32x4 __attribute__((ext_vector_type(4)));
typedef float f4v __attribute__((ext_vector_type(4)));   // clang-native for nontemporal builtins
typedef unsigned short u16;

// Workspace layout (bytes).
#define WS_HDR   0
#define WS_SORT  1024
#define WS_XBF   21504      // u16[NT*NH]
#define WS_GT    2118656    // u16[NE*NI*NH]  gate^T [E][I][H]
#define WS_UT    25187328   // u16[NE*NI*NH]  up^T
#define WS_DT    48256000   // u16[NE*NH*NI]  down^T [E][H][I]
#define WS_HB    71324672   // u16[PADSLOTS*NI]

__device__ __forceinline__ u16 f2b(float f) {
  union { float f; uint32_t u; } c; c.f = f;
  uint32_t u = c.u;
  return (u16)((u + 0x7FFFu + ((u >> 16) & 1u)) >> 16);  // RNE
}

__device__ __forceinline__ void llds16(const void* g, void* l) {
  __builtin_amdgcn_global_load_lds(
      (const __attribute__((address_space(1))) void*)g,
      (__attribute__((address_space(3))) void*)l, 16, 0, 0);
}

// Shared transpose-convert stripe: [K][N] fp32 -> [N][K] bf16, 64k x 128n per block.
// smem must hold 2*64*72 u16. 256 threads.
__device__ __forceinline__ void transcvt_stripe(const float* __restrict__ src,
                                                u16* __restrict__ dst,
                                                int K, int N, int k0, int n0,
                                                u16* smem, int tid) {
  u16 (*t2)[64][72] = (u16(*)[64][72])smem;
  int r = tid >> 4, c = tid & 15;          // 16 x 16 over (row, col16)
  f4v v[2][4];
#pragma unroll
  for (int t = 0; t < 2; ++t)
#pragma unroll
    for (int i = 0; i < 4; ++i)
      v[t][i] = __builtin_nontemporal_load(
          (const f4v*)&src[(size_t)(k0 + r + 16 * i) * N + n0 + t * 64 + c * 4]);
#pragma unroll
  for (int t = 0; t < 2; ++t)
#pragma unroll
    for (int i = 0; i < 4; ++i) {
      ushort4 o;
      o.x = f2b(v[t][i].x); o.y = f2b(v[t][i].y); o.z = f2b(v[t][i].z); o.w = f2b(v[t][i].w);
      *(ushort4*)&t2[t][r + 16 * i][c * 4] = o;
    }
  __syncthreads();
#pragma unroll
  for (int t = 0; t < 2; ++t)
#pragma unroll
    for (int i = 0; i < 2; ++i) {
      int idx = i * 256 + tid;
      int n = idx >> 3, kc = idx & 7;
      u16 o[8];
#pragma unroll
      for (int j = 0; j < 8; ++j) o[j] = t2[t][kc * 8 + j][n];
      *(short8*)&dst[(size_t)(n0 + t * 64 + n) * K + k0 + kc * 8] = *(const short8*)o;
    }
}

// ---------------- K1: bucket + gate/up transpose-convert + x convert + out zero ----------------
// Grid (176, 18): y<16 -> tensor=y>>3 (0 gate, 1 up), e=y&7, stripe=x (11 nb x 16 kb);
// y==16 -> x convert; y==17: x==0 bucket, 1<=x<=64 zero out (64 KB each).
__global__ __launch_bounds__(256) void k1_prep(
    const float* __restrict__ gw, const float* __restrict__ uw, const float* __restrict__ hs,
    const int* __restrict__ sel,
    u16* __restrict__ gT, u16* __restrict__ uT, u16* __restrict__ xbf,
    int* __restrict__ hdr, int* __restrict__ sorted, float* __restrict__ outz) {
  int tid = threadIdx.x;
  int y = blockIdx.y;
  if (y == 16) {  // hidden_states convert (1M elements)
    for (int i = blockIdx.x * 256 + tid; i * 4 < NT * NH; i += 176 * 256) {
      f4v v = __builtin_nontemporal_load((const f4v*)&hs[i * 4]);
      ushort4 o;
      o.x = f2b(v.x); o.y = f2b(v.y); o.z = f2b(v.z); o.w = f2b(v.w);
      *(ushort4*)&xbf[i * 4] = o;
    }
    return;
  }
  if (y == 17) {
    int x = blockIdx.x;
    if (x >= 1 && x <= 64) {  // zero out: 64 blocks x 64 KB
      int base = (x - 1) * 16384;
      f4v z = {0.f, 0.f, 0.f, 0.f};
#pragma unroll
      for (int i = 0; i < 16; ++i)
        *(f4v*)&outz[base + (i * 256 + tid) * 4] = z;
      return;
    }
    if (x != 0) return;
    // bucket (single block)
    __shared__ int cnt[NE], fill[NE], poff_s[NE + 1];
    if (tid < NE) { cnt[tid] = 0; fill[tid] = 0; }
    __syncthreads();
    for (int i = tid; i < NA; i += 256) atomicAdd(&cnt[sel[i]], 1);
    __syncthreads();
    if (tid == 0) {
      int off = 0, nt = 0;
      for (int e = 0; e < NE; ++e) {
        poff_s[e] = off;
        int tiles = (cnt[e] + BM - 1) / BM;
        for (int j = 0; j < tiles; ++j) { hdr[32 + nt] = e; hdr[80 + nt] = off + j * BM; ++nt; }
        off += tiles * BM;
      }
      poff_s[NE] = off;
      hdr[17] = nt;
      for (int e = 0; e < NE; ++e) hdr[e] = cnt[e];
      for (int e = 0; e <= NE; ++e) hdr[8 + e] = poff_s[e];
    }
    __syncthreads();
    for (int i = tid; i < PADSLOTS; i += 256) sorted[i] = -1;
    __syncthreads();
    for (int i = tid; i < NA; i += 256) {
      int e = sel[i];
      int p = atomicAdd(&fill[e], 1);
      sorted[poff_s[e] + p] = i;
    }
    return;
  }
  __shared__ u16 smem[2 * 64 * 72];
  int tensor = y >> 3, e = y & 7;
  const float* src = (tensor == 0) ? gw : uw;
  u16* dst = (tensor == 0) ? gT : uT;
  src += (size_t)e * NH * NI;
  dst += (size_t)e * NH * NI;
  int nb = blockIdx.x % 11, kb = blockIdx.x / 11;   // K=NH (16 kb), N=NI (11 nb)
  transcvt_stripe(src, dst, NH, NI, kb * 64, nb * 128, smem, tid);
}

// ---------------- K2: gemm1 (128x128) interleaved 1:3 with down-convert stripes ----------------
// Grid 1848. gemm when (b&3)==0 && b<1760 -> tile idx b>>2 (440 = 40 tiles x 11 n0);
// else stripe idx = b - min(440, (b+3)>>2)  (1408 stripes).
// Interleaving keeps HBM-bound stripes co-resident with latency-bound gemm blocks
// for the whole dispatch (R6 showed gemm-first ordering leaves a serial stripe tail).
__global__ __launch_bounds__(256, 3) void k2_gemm1(
    const u16* __restrict__ xbf, const u16* __restrict__ gT, const u16* __restrict__ uT,
    u16* __restrict__ hbuf, const int* __restrict__ hdr, const int* __restrict__ sorted,
    const float* __restrict__ dw, u16* __restrict__ dT) {
  __shared__ u16 smem[24576];   // 48 KB shared across roles
  int b = blockIdx.x;
  int tid = threadIdx.x;

  bool is_gemm = ((b & 3) == 0) && (b < 1760);
  if (!is_gemm) {   // down-weight transpose-convert: 1408 stripes
    int ng = (b + 3) >> 2; if (ng > 440) ng = 440;
    int idx = b - ng;
    int e = idx / 176, stripe = idx % 176;
    int nb = stripe % 8, kb = stripe / 8;           // K=NI (22 kb), N=NH (8 nb)
    const float* src = dw + (size_t)e * NI * NH;
    u16* dst = dT + (size_t)e * NI * NH;
    transcvt_stripe(src, dst, NI, NH, kb * 64, nb * 128, smem, tid);
    return;
  }

  // ---- gemm1: h = silu(x@gate) * (x@up), 128x128 tile, BK=64, XOR-swizzled LDS ----
  int g = b >> 2;             // 0..439
  int tile = g % 40;
  if (tile >= hdr[17]) return;
  int e = hdr[32 + tile];
  int slot0 = hdr[80 + tile];
  int n0 = (g / 40) * 128;

  u16* sA  = smem;            // 128*64
  u16* sBg = smem + 8192;     // 128*64
  u16* sBu = smem + 16384;    // 128*64

  const u16* aptr[4];
  for (int s = 0; s < 4; ++s) {
    int idx = s * 256 + tid;
    int row = idx >> 3, c = idx & 7;
    int kc = c ^ (row & 7);
    int as = sorted[slot0 + row];
    int trow = (as >= 0) ? (as >> 2) : 0;
    aptr[s] = xbf + (size_t)trow * NH + kc * 8;
  }
  const u16 *bgp[4], *bup[4];
  for (int s = 0; s < 4; ++s) {
    int idx = s * 256 + tid;
    int n = idx >> 3, c = idx & 7;
    int kc = c ^ (n & 7);
    size_t o = ((size_t)e * NI + n0 + n) * NH + kc * 8;
    bgp[s] = gT + o; bup[s] = uT + o;
  }

  int lane = tid & 63, wave = tid >> 6;
  int wm = wave >> 1, wn = wave & 1;
  int l15 = lane & 15, quad = lane >> 4;
  int sw = l15 & 7;

  f32x4 accg[4][4] = {}; f32x4 accu[4][4] = {};

  for (int kt = 0; kt < NH / 64; ++kt) {
    int ko = kt * 64;
    for (int s = 0; s < 4; ++s) llds16(aptr[s] + ko, &sA[(s * 256 + tid) * 8]);
    for (int s = 0; s < 4; ++s) llds16(bgp[s] + ko, &sBg[(s * 256 + tid) * 8]);
    for (int s = 0; s < 4; ++s) llds16(bup[s] + ko, &sBu[(s * 256 + tid) * 8]);
    __syncthreads();
    for (int ks = 0; ks < 2; ++ks) {
      int pos = ((ks * 4 + quad) ^ sw) * 8;
      short8 av[4], bg[4], bu[4];
      for (int mf = 0; mf < 4; ++mf)
        av[mf] = *(const short8*)&sA[(wm * 64 + mf * 16 + l15) * 64 + pos];
      for (int nf = 0; nf < 4; ++nf) {
        bg[nf] = *(const short8*)&sBg[(wn * 64 + nf * 16 + l15) * 64 + pos];
        bu[nf] = *(const short8*)&sBu[(wn * 64 + nf * 16 + l15) * 64 + pos];
      }
      for (int mf = 0; mf < 4; ++mf)
        for (int nf = 0; nf < 4; ++nf) {
          accg[mf][nf] = __builtin_amdgcn_mfma_f32_16x16x32_bf16(av[mf], bg[nf], accg[mf][nf], 0, 0, 0);
          accu[mf][nf] = __builtin_amdgcn_mfma_f32_16x16x32_bf16(av[mf], bu[nf], accu[mf][nf], 0, 0, 0);
        }
    }
    __syncthreads();
  }

  for (int mf = 0; mf < 4; ++mf)
    for (int nf = 0; nf < 4; ++nf)
      for (int r = 0; r < 4; ++r) {
        int row = wm * 64 + mf * 16 + quad * 4 + r;
        int col = n0 + wn * 64 + nf * 16 + l15;
        float g2 = accg[mf][nf][r], u = accu[mf][nf][r];
        float hv = (g2 / (1.f + __expf(-g2))) * u;
        hbuf[(size_t)(slot0 + row) * NI + col] = f2b(hv);
      }
}

// ---------------- K3: down projection 128x128 + fused weighted atomic combine ----------------
__global__ __launch_bounds__(256, 4) void k3_gemm2(
    const u16* __restrict__ hbuf, const u16* __restrict__ dT,
    const float* __restrict__ rw, float* __restrict__ out,
    const int* __restrict__ hdr, const int* __restrict__ sorted) {
  int tile = blockIdx.x;
  if (tile >= hdr[17]) return;
  int e = hdr[32 + tile];
  int slot0 = hdr[80 + tile];
  int n0 = blockIdx.y * 128;
  int tid = threadIdx.x;

  __shared__ u16 sA[128 * 64];   // [m][k], swizzled
  __shared__ u16 sB[128 * 64];   // [n][k], swizzled

  const u16 *ap[4], *bp[4];
  for (int s = 0; s < 4; ++s) {
    int idx = s * 256 + tid;
    int r = idx >> 3, c = idx & 7;
    int kc = c ^ (r & 7);
    ap[s] = hbuf + (size_t)(slot0 + r) * NI + kc * 8;
    bp[s] = dT + ((size_t)e * NH + n0 + r) * NI + kc * 8;
  }

  int lane = tid & 63, wave = tid >> 6;
  int wm = wave >> 1, wn = wave & 1;
  int l15 = lane & 15, quad = lane >> 4;
  int sw = l15 & 7;

  f32x4 acc[4][4] = {};

  for (int kt = 0; kt < NI / 64; ++kt) {
    int ko = kt * 64;
    for (int s = 0; s < 4; ++s) llds16(ap[s] + ko, &sA[(s * 256 + tid) * 8]);
    for (int s = 0; s < 4; ++s) llds16(bp[s] + ko, &sB[(s * 256 + tid) * 8]);
    __syncthreads();
    for (int ks = 0; ks < 2; ++ks) {
      int pos = ((ks * 4 + quad) ^ sw) * 8;
      short8 av[4], bv[4];
      for (int mf = 0; mf < 4; ++mf)
        av[mf] = *(const short8*)&sA[(wm * 64 + mf * 16 + l15) * 64 + pos];
      for (int nf = 0; nf < 4; ++nf)
        bv[nf] = *(const short8*)&sB[(wn * 64 + nf * 16 + l15) * 64 + pos];
      for (int mf = 0; mf < 4; ++mf)
        for (int nf = 0; nf < 4; ++nf)
          acc[mf][nf] = __builtin_amdgcn_mfma_f32_16x16x32_bf16(av[mf], bv[nf], acc[mf][nf], 0, 0, 0);
    }
    __syncthreads();
  }

  // weighted combine: out[token] += rw[assignment] * down_row
  for (int mf = 0; mf < 4; ++mf) {
    int rowb = wm * 64 + mf * 16 + quad * 4;
    for (int r = 0; r < 4; ++r) {
      int as = sorted[slot0 + rowb + r];
      if (as < 0) continue;
      float w = rw[as];
      float* orow = out + (size_t)(as >> 2) * NH + n0 + wn * 64;
      for (int nf = 0; nf < 4; ++nf)
        atomicAdd(&orow[nf * 16 + l15], w * acc[mf][nf][r]);
    }
  }
}

extern "C" void kernel_launch(void* const* d_in, const int* in_sizes, int n_in,
                              void* d_out, int out_size, void* d_ws, size_t ws_size,
                              hipStream_t stream) {
  const float* hs  = (const float*)d_in[0];
  const float* rw  = (const float*)d_in[1];
  const float* gw  = (const float*)d_in[2];
  const float* uw  = (const float*)d_in[3];
  const float* dw  = (const float*)d_in[4];
  const int*   sel = (const int*)d_in[5];
  float* out = (float*)d_out;

  char* ws = (char*)d_ws;
  int*  hdr    = (int*)(ws + WS_HDR);
  int*  sorted = (int*)(ws + WS_SORT);
  u16*  xbf    = (u16*)(ws + WS_XBF);
  u16*  gT     = (u16*)(ws + WS_GT);
  u16*  uT     = (u16*)(ws + WS_UT);
  u16*  dT     = (u16*)(ws + WS_DT);
  u16*  hb     = (u16*)(ws + WS_HB);

  hipLaunchKernelGGL(k1_prep, dim3(176, 18), dim3(256), 0, stream,
                     gw, uw, hs, sel, gT, uT, xbf, hdr, sorted, out);
  hipLaunchKernelGGL(k2_gemm1, dim3(1848), dim3(256), 0, stream,
                     xbf, gT, uT, hb, hdr, sorted, dw, dT);
  hipLaunchKernelGGL(k3_gemm2, dim3(MAXTILES, NH / 128), dim3(256), 0, stream,
                     hb, dT, rw, out, hdr, sorted);
}

// Round 8
// 243.254 us; speedup vs baseline: 1.9349x; 1.9349x over previous
//
#include <hip/hip_runtime.h>
#include <hip/hip_bf16.h>
#include <cstdint>
#include <cstddef>

// Problem constants (DeepseekV3Experts: T=1024 H=1024 I=1408 E=8 K=4)
#define NE 8
#define NT 1024
#define NK 4
#define NH 1024
#define NI 1408
#define NA (NT * NK)      // 4096 assignments
#define BM 128            // row tile
#define MAXTILES 40
#define PADSLOTS 5120

typedef short short8 __attribute__((ext_vector_type(8)));
typedef float f32x4 __attribute__((ext_vector_type(4)));
typedef float f4v __attribute__((ext_vector_type(4)));   // clang-native for nontemporal builtins
typedef unsigned short u16;

// Workspace layout (bytes).
#define WS_HDR   0
#define WS_SORT  1024
#define WS_XBF   21504      // u16[NT*NH]
#define WS_GT    2118656    // u16[NE*NI*NH]  gate^T [E][I][H]
#define WS_UT    25187328   // u16[NE*NI*NH]  up^T
#define WS_DT    48256000   // u16[NE*NH*NI]  down^T [E][H][I]
#define WS_HB    71324672   // u16[PADSLOTS*NI]

__device__ __forceinline__ u16 f2b(float f) {
  union { float f; uint32_t u; } c; c.f = f;
  uint32_t u = c.u;
  return (u16)((u + 0x7FFFu + ((u >> 16) & 1u)) >> 16);  // RNE
}

__device__ __forceinline__ void llds16(const void* g, void* l) {
  __builtin_amdgcn_global_load_lds(
      (const __attribute__((address_space(1))) void*)g,
      (__attribute__((address_space(3))) void*)l, 16, 0, 0);
}

// Shared transpose-convert stripe: [K][N] fp32 -> [N][K] bf16, 64k x 128n per block.
// smem must hold 2*64*72 u16. 256 threads.
__device__ __forceinline__ void transcvt_stripe(const float* __restrict__ src,
                                                u16* __restrict__ dst,
                                                int K, int N, int k0, int n0,
                                                u16* smem, int tid) {
  u16 (*t2)[64][72] = (u16(*)[64][72])smem;
  int r = tid >> 4, c = tid & 15;          // 16 x 16 over (row, col16)
  f4v v[2][4];
#pragma unroll
  for (int t = 0; t < 2; ++t)
#pragma unroll
    for (int i = 0; i < 4; ++i)
      v[t][i] = __builtin_nontemporal_load(
          (const f4v*)&src[(size_t)(k0 + r + 16 * i) * N + n0 + t * 64 + c * 4]);
#pragma unroll
  for (int t = 0; t < 2; ++t)
#pragma unroll
    for (int i = 0; i < 4; ++i) {
      ushort4 o;
      o.x = f2b(v[t][i].x); o.y = f2b(v[t][i].y); o.z = f2b(v[t][i].z); o.w = f2b(v[t][i].w);
      *(ushort4*)&t2[t][r + 16 * i][c * 4] = o;
    }
  __syncthreads();
#pragma unroll
  for (int t = 0; t < 2; ++t)
#pragma unroll
    for (int i = 0; i < 2; ++i) {
      int idx = i * 256 + tid;
      int n = idx >> 3, kc = idx & 7;
      u16 o[8];
#pragma unroll
      for (int j = 0; j < 8; ++j) o[j] = t2[t][kc * 8 + j][n];
      *(short8*)&dst[(size_t)(n0 + t * 64 + n) * K + k0 + kc * 8] = *(const short8*)o;
    }
}

// ---------------- K1: all conversions + bucket + out zero (pure HBM-bound work) ----------------
// Grid (176, 26): y<16 -> gate/up stripes (tensor=y>>3, e=y&7; x: nb=x%11? no: 11 nb x 16 kb);
// y in 16..23 -> down stripes (e=y-16; nb=x%8, kb=x/8);
// y==24 -> x convert; y==25: x==0 bucket, 1<=x<=64 zero out (64 KB each).
__global__ __launch_bounds__(256) void k1_prep(
    const float* __restrict__ gw, const float* __restrict__ uw, const float* __restrict__ dw,
    const float* __restrict__ hs, const int* __restrict__ sel,
    u16* __restrict__ gT, u16* __restrict__ uT, u16* __restrict__ dT, u16* __restrict__ xbf,
    int* __restrict__ hdr, int* __restrict__ sorted, float* __restrict__ outz) {
  int tid = threadIdx.x;
  int y = blockIdx.y;
  if (y == 24) {  // hidden_states convert (1M elements)
    for (int i = blockIdx.x * 256 + tid; i * 4 < NT * NH; i += 176 * 256) {
      f4v v = __builtin_nontemporal_load((const f4v*)&hs[i * 4]);
      ushort4 o;
      o.x = f2b(v.x); o.y = f2b(v.y); o.z = f2b(v.z); o.w = f2b(v.w);
      *(ushort4*)&xbf[i * 4] = o;
    }
    return;
  }
  if (y == 25) {
    int x = blockIdx.x;
    if (x >= 1 && x <= 64) {  // zero out: 64 blocks x 64 KB
      int base = (x - 1) * 16384;
      f4v z = {0.f, 0.f, 0.f, 0.f};
#pragma unroll
      for (int i = 0; i < 16; ++i)
        *(f4v*)&outz[base + (i * 256 + tid) * 4] = z;
      return;
    }
    if (x != 0) return;
    // bucket (single block)
    __shared__ int cnt[NE], fill[NE], poff_s[NE + 1];
    if (tid < NE) { cnt[tid] = 0; fill[tid] = 0; }
    __syncthreads();
    for (int i = tid; i < NA; i += 256) atomicAdd(&cnt[sel[i]], 1);
    __syncthreads();
    if (tid == 0) {
      int off = 0, nt = 0;
      for (int e = 0; e < NE; ++e) {
        poff_s[e] = off;
        int tiles = (cnt[e] + BM - 1) / BM;
        for (int j = 0; j < tiles; ++j) { hdr[32 + nt] = e; hdr[80 + nt] = off + j * BM; ++nt; }
        off += tiles * BM;
      }
      poff_s[NE] = off;
      hdr[17] = nt;
      for (int e = 0; e < NE; ++e) hdr[e] = cnt[e];
      for (int e = 0; e <= NE; ++e) hdr[8 + e] = poff_s[e];
    }
    __syncthreads();
    for (int i = tid; i < PADSLOTS; i += 256) sorted[i] = -1;
    __syncthreads();
    for (int i = tid; i < NA; i += 256) {
      int e = sel[i];
      int p = atomicAdd(&fill[e], 1);
      sorted[poff_s[e] + p] = i;
    }
    return;
  }
  __shared__ u16 smem[2 * 64 * 72];
  if (y < 16) {   // gate/up: K=NH (16 kb), N=NI (11 nb)
    int tensor = y >> 3, e = y & 7;
    const float* src = ((tensor == 0) ? gw : uw) + (size_t)e * NH * NI;
    u16* dst = ((tensor == 0) ? gT : uT) + (size_t)e * NH * NI;
    int nb = blockIdx.x % 11, kb = blockIdx.x / 11;
    transcvt_stripe(src, dst, NH, NI, kb * 64, nb * 128, smem, tid);
  } else {        // down: K=NI (22 kb), N=NH (8 nb)
    int e = y - 16;
    const float* src = dw + (size_t)e * NI * NH;
    u16* dst = dT + (size_t)e * NI * NH;
    int nb = blockIdx.x % 8, kb = blockIdx.x / 8;
    transcvt_stripe(src, dst, NI, NH, kb * 64, nb * 128, smem, tid);
  }
}

// ---------------- K2: pure gemm1, 128x128 tile, BK=64, XOR-swizzled LDS ----------------
// Grid 440: tile = b%40, n0 = (b/40)*128.
__global__ __launch_bounds__(256, 2) void k2_gemm1(
    const u16* __restrict__ xbf, const u16* __restrict__ gT, const u16* __restrict__ uT,
    u16* __restrict__ hbuf, const int* __restrict__ hdr, const int* __restrict__ sorted) {
  __shared__ u16 smem[24576];   // 48 KB
  int b = blockIdx.x;
  int tid = threadIdx.x;

  int tile = b % 40;
  if (tile >= hdr[17]) return;
  int e = hdr[32 + tile];
  int slot0 = hdr[80 + tile];
  int n0 = (b / 40) * 128;

  u16* sA  = smem;            // 128*64
  u16* sBg = smem + 8192;     // 128*64
  u16* sBu = smem + 16384;    // 128*64

  const u16* aptr[4];
  for (int s = 0; s < 4; ++s) {
    int idx = s * 256 + tid;
    int row = idx >> 3, c = idx & 7;
    int kc = c ^ (row & 7);
    int as = sorted[slot0 + row];
    int trow = (as >= 0) ? (as >> 2) : 0;
    aptr[s] = xbf + (size_t)trow * NH + kc * 8;
  }
  const u16 *bgp[4], *bup[4];
  for (int s = 0; s < 4; ++s) {
    int idx = s * 256 + tid;
    int n = idx >> 3, c = idx & 7;
    int kc = c ^ (n & 7);
    size_t o = ((size_t)e * NI + n0 + n) * NH + kc * 8;
    bgp[s] = gT + o; bup[s] = uT + o;
  }

  int lane = tid & 63, wave = tid >> 6;
  int wm = wave >> 1, wn = wave & 1;
  int l15 = lane & 15, quad = lane >> 4;
  int sw = l15 & 7;

  f32x4 accg[4][4] = {}; f32x4 accu[4][4] = {};

  for (int kt = 0; kt < NH / 64; ++kt) {
    int ko = kt * 64;
    for (int s = 0; s < 4; ++s) llds16(aptr[s] + ko, &sA[(s * 256 + tid) * 8]);
    for (int s = 0; s < 4; ++s) llds16(bgp[s] + ko, &sBg[(s * 256 + tid) * 8]);
    for (int s = 0; s < 4; ++s) llds16(bup[s] + ko, &sBu[(s * 256 + tid) * 8]);
    __syncthreads();
    for (int ks = 0; ks < 2; ++ks) {
      int pos = ((ks * 4 + quad) ^ sw) * 8;
      short8 av[4], bg[4], bu[4];
      for (int mf = 0; mf < 4; ++mf)
        av[mf] = *(const short8*)&sA[(wm * 64 + mf * 16 + l15) * 64 + pos];
      for (int nf = 0; nf < 4; ++nf) {
        bg[nf] = *(const short8*)&sBg[(wn * 64 + nf * 16 + l15) * 64 + pos];
        bu[nf] = *(const short8*)&sBu[(wn * 64 + nf * 16 + l15) * 64 + pos];
      }
      for (int mf = 0; mf < 4; ++mf)
        for (int nf = 0; nf < 4; ++nf) {
          accg[mf][nf] = __builtin_amdgcn_mfma_f32_16x16x32_bf16(av[mf], bg[nf], accg[mf][nf], 0, 0, 0);
          accu[mf][nf] = __builtin_amdgcn_mfma_f32_16x16x32_bf16(av[mf], bu[nf], accu[mf][nf], 0, 0, 0);
        }
    }
    __syncthreads();
  }

  for (int mf = 0; mf < 4; ++mf)
    for (int nf = 0; nf < 4; ++nf)
      for (int r = 0; r < 4; ++r) {
        int row = wm * 64 + mf * 16 + quad * 4 + r;
        int col = n0 + wn * 64 + nf * 16 + l15;
        float g2 = accg[mf][nf][r], u = accu[mf][nf][r];
        float hv = (g2 / (1.f + __expf(-g2))) * u;
        hbuf[(size_t)(slot0 + row) * NI + col] = f2b(hv);
      }
}

// ---------------- K3: down projection 128x128 + fused weighted atomic combine ----------------
__global__ __launch_bounds__(256, 4) void k3_gemm2(
    const u16* __restrict__ hbuf, const u16* __restrict__ dT,
    const float* __restrict__ rw, float* __restrict__ out,
    const int* __restrict__ hdr, const int* __restrict__ sorted) {
  int tile = blockIdx.x;
  if (tile >= hdr[17]) return;
  int e = hdr[32 + tile];
  int slot0 = hdr[80 + tile];
  int n0 = blockIdx.y * 128;
  int tid = threadIdx.x;

  __shared__ u16 sA[128 * 64];   // [m][k], swizzled
  __shared__ u16 sB[128 * 64];   // [n][k], swizzled

  const u16 *ap[4], *bp[4];
  for (int s = 0; s < 4; ++s) {
    int idx = s * 256 + tid;
    int r = idx >> 3, c = idx & 7;
    int kc = c ^ (r & 7);
    ap[s] = hbuf + (size_t)(slot0 + r) * NI + kc * 8;
    bp[s] = dT + ((size_t)e * NH + n0 + r) * NI + kc * 8;
  }

  int lane = tid & 63, wave = tid >> 6;
  int wm = wave >> 1, wn = wave & 1;
  int l15 = lane & 15, quad = lane >> 4;
  int sw = l15 & 7;

  f32x4 acc[4][4] = {};

  for (int kt = 0; kt < NI / 64; ++kt) {
    int ko = kt * 64;
    for (int s = 0; s < 4; ++s) llds16(ap[s] + ko, &sA[(s * 256 + tid) * 8]);
    for (int s = 0; s < 4; ++s) llds16(bp[s] + ko, &sB[(s * 256 + tid) * 8]);
    __syncthreads();
    for (int ks = 0; ks < 2; ++ks) {
      int pos = ((ks * 4 + quad) ^ sw) * 8;
      short8 av[4], bv[4];
      for (int mf = 0; mf < 4; ++mf)
        av[mf] = *(const short8*)&sA[(wm * 64 + mf * 16 + l15) * 64 + pos];
      for (int nf = 0; nf < 4; ++nf)
        bv[nf] = *(const short8*)&sB[(wn * 64 + nf * 16 + l15) * 64 + pos];
      for (int mf = 0; mf < 4; ++mf)
        for (int nf = 0; nf < 4; ++nf)
          acc[mf][nf] = __builtin_amdgcn_mfma_f32_16x16x32_bf16(av[mf], bv[nf], acc[mf][nf], 0, 0, 0);
    }
    __syncthreads();
  }

  // weighted combine: out[token] += rw[assignment] * down_row
  for (int mf = 0; mf < 4; ++mf) {
    int rowb = wm * 64 + mf * 16 + quad * 4;
    for (int r = 0; r < 4; ++r) {
      int as = sorted[slot0 + rowb + r];
      if (as < 0) continue;
      float w = rw[as];
      float* orow = out + (size_t)(as >> 2) * NH + n0 + wn * 64;
      for (int nf = 0; nf < 4; ++nf)
        atomicAdd(&orow[nf * 16 + l15], w * acc[mf][nf][r]);
    }
  }
}

extern "C" void kernel_launch(void* const* d_in, const int* in_sizes, int n_in,
                              void* d_out, int out_size, void* d_ws, size_t ws_size,
                              hipStream_t stream) {
  const float* hs  = (const float*)d_in[0];
  const float* rw  = (const float*)d_in[1];
  const float* gw  = (const float*)d_in[2];
  const float* uw  = (const float*)d_in[3];
  const float* dw  = (const float*)d_in[4];
  const int*   sel = (const int*)d_in[5];
  float* out = (float*)d_out;

  char* ws = (char*)d_ws;
  int*  hdr    = (int*)(ws + WS_HDR);
  int*  sorted = (int*)(ws + WS_SORT);
  u16*  xbf    = (u16*)(ws + WS_XBF);
  u16*  gT     = (u16*)(ws + WS_GT);
  u16*  uT     = (u16*)(ws + WS_UT);
  u16*  dT     = (u16*)(ws + WS_DT);
  u16*  hb     = (u16*)(ws + WS_HB);

  hipLaunchKernelGGL(k1_prep, dim3(176, 26), dim3(256), 0, stream,
                     gw, uw, dw, hs, sel, gT, uT, dT, xbf, hdr, sorted, out);
  hipLaunchKernelGGL(k2_gemm1, dim3(440), dim3(256), 0, stream,
                     xbf, gT, uT, hb, hdr, sorted);
  hipLaunchKernelGGL(k3_gemm2, dim3(MAXTILES, NH / 128), dim3(256), 0, stream,
                     hb, dT, rw, out, hdr, sorted);
}